// Round 8
// baseline (518.678 us; speedup 1.0000x reference)
//
#include <hip/hip_runtime.h>
#include <math.h>

typedef short s16x8 __attribute__((ext_vector_type(8)));
typedef __bf16 b16x8 __attribute__((ext_vector_type(8)));
typedef float f32x4 __attribute__((ext_vector_type(4)));
typedef unsigned int u32x4 __attribute__((ext_vector_type(4)));

__device__ inline short f2bf(float f) {
    unsigned u = __float_as_uint(f);
    unsigned r = u + 0x7FFFu + ((u >> 16) & 1u);   // RNE
    return (short)(r >> 16);
}
__device__ inline float bf2f(unsigned short u) {
    return __uint_as_float(((unsigned)u) << 16);
}

// async global->LDS, 16B per lane; lds dest = wave-uniform base + lane*16
#define GLDS16(g, l)                                                            \
    __builtin_amdgcn_global_load_lds(                                           \
        (const __attribute__((address_space(1))) void*)(g),                     \
        (__attribute__((address_space(3))) void*)(l), 16, 0, 0)

// ---------------- CSR build ----------------

__global__ void count_kernel(const int* __restrict__ dst, int* __restrict__ cnt, int E) {
    int e = blockIdx.x * blockDim.x + threadIdx.x;
    if (e < E) atomicAdd(&cnt[dst[e]], 1);
}

__global__ __launch_bounds__(1024) void blockscan_kernel(const int* __restrict__ cnt,
                                                         int* __restrict__ rp,
                                                         int* __restrict__ bsum, int n) {
    __shared__ int sdata[1024];
    int tid = threadIdx.x;
    int i = blockIdx.x * 1024 + tid;
    int v = (i < n) ? cnt[i] : 0;
    sdata[tid] = v;
    __syncthreads();
    for (int off = 1; off < 1024; off <<= 1) {
        int t = 0;
        if (tid >= off) t = sdata[tid - off];
        __syncthreads();
        sdata[tid] += t;
        __syncthreads();
    }
    if (i < n) rp[i] = sdata[tid] - v;       // local exclusive
    if (tid == 1023) bsum[blockIdx.x] = sdata[1023];
}

__global__ void topscan_kernel(int* bsum, int nb) {
    int lane = threadIdx.x;                   // 64 threads
    int carry = 0;
    for (int base = 0; base < nb; base += 64) {
        int idx = base + lane;
        int orig = (idx < nb) ? bsum[idx] : 0;
        int v = orig;
        for (int off = 1; off < 64; off <<= 1) {
            int t = __shfl_up(v, off, 64);
            if (lane >= off) v += t;
        }
        if (idx < nb) bsum[idx] = carry + v - orig;   // exclusive
        carry += __shfl(v, 63, 64);
    }
}

__global__ __launch_bounds__(1024) void fixup_kernel(int* __restrict__ rp,
                                                     const int* __restrict__ bsum,
                                                     const int* __restrict__ cnt,
                                                     int* __restrict__ cursor,
                                                     float* __restrict__ dinv,
                                                     int n, int E) {
    int i = blockIdx.x * 1024 + threadIdx.x;
    if (i < n) {
        int r = rp[i] + bsum[blockIdx.x];
        rp[i] = r;
        cursor[i] = r;
        dinv[i] = rsqrtf((float)cnt[i] + 1.0f);
    }
    if (i == 0) rp[n] = E;
}

__global__ void fill_kernel(const int* __restrict__ src, const int* __restrict__ dst,
                            int* __restrict__ cursor, const float* __restrict__ dinv,
                            int* __restrict__ csrc, float* __restrict__ cw, int E) {
    int e = blockIdx.x * blockDim.x + threadIdx.x;
    if (e >= E) return;
    int d = dst[e];
    int s = src[e];
    int p = atomicAdd(&cursor[d], 1);
    csrc[p] = s;
    cw[p] = dinv[s] * dinv[d];
}

// ---------------- weight pre-transpose to fragment-ready bf16 ----------------
// Wt chunk layout: [c = k0/32][b = n0/128][nt 0..7][lane 0..63][j 0..7]
//   value = W[c*32 + (lane>>4)*8 + j][b*128 + nt*16 + (lane&15)]

__global__ void make_wt_kernel(const float* __restrict__ W, short* __restrict__ Wt,
                               int K, int N) {
    int idx = blockIdx.x * blockDim.x + threadIdx.x;
    if (idx >= K * N) return;
    int NB = N >> 7;
    int j = idx & 7;
    int l = (idx >> 3) & 63;
    int nt = (idx >> 9) & 7;
    int rest = idx >> 12;
    int b = rest % NB;
    int c = rest / NB;
    int k = c * 32 + (l >> 4) * 8 + j;
    int n = b * 128 + nt * 16 + (l & 15);
    Wt[idx] = f2bf(W[(size_t)k * N + n]);
}

// ---------------- x fp32 -> bf16 A-fragment-ready conversion ----------------
// unit u = ((mt*24 + c)*4 + q)*16 + rl  <->  row = mt*16+rl, k = c*32+q*8 (8 elems, 16B).
// Writes are lane-contiguous 16B; rows >= M zero-filled.

__global__ __launch_bounds__(256) void convx_kernel(const float* __restrict__ x,
                                                    s16x8* __restrict__ xf,
                                                    int M, int units) {
    int u = blockIdx.x * 256 + threadIdx.x;
    if (u >= units) return;
    int rl = u & 15;
    int q = (u >> 4) & 3;
    int rest = u >> 6;
    int c = rest % 24;
    int mt = rest / 24;
    int row = mt * 16 + rl;
    s16x8 v = (s16x8){0, 0, 0, 0, 0, 0, 0, 0};
    if (row < M) {
        const float* p = x + (size_t)row * 768 + c * 32 + q * 8;
        float4 f0 = *(const float4*)p;
        float4 f1 = *(const float4*)(p + 4);
        v[0] = f2bf(f0.x); v[1] = f2bf(f0.y); v[2] = f2bf(f0.z); v[3] = f2bf(f0.w);
        v[4] = f2bf(f1.x); v[5] = f2bf(f1.y); v[6] = f2bf(f1.z); v[7] = f2bf(f1.w);
    }
    xf[u] = v;
}

// ---------------- GEMM1: C[M x 256](bf16) = xf(frag-ready) @ Wt1(frag-ready) ----------------
// Block = 32 rows x 256 cols, 256 threads = 4 waves (wave w -> cols w*64..w*64+63).
// A panel = contiguous 48 KB of xf staged via global_load_lds (12 instrs/wave),
// ONE barrier, then barrier-free K-loop: conflict-free ds_read_b128 + B from L2 + MFMA.

__global__ __launch_bounds__(256, 3) void gemm1_kernel(const s16x8* __restrict__ xf,
                                                       const short* __restrict__ Wt,
                                                       unsigned short* __restrict__ Cb,
                                                       int M) {
    __shared__ s16x8 As[3072];                 // 48 KB: [mt 0..1][c 0..23][lane 0..63]

    const int tid = threadIdx.x;
    const int lane = tid & 63;
    const int wave = tid >> 6;
    const int m0 = blockIdx.x * 32;
    const s16x8* src = xf + (size_t)blockIdx.x * 3072;

#pragma unroll
    for (int i = 0; i < 12; ++i) {
        int blk = wave * 12 + i;
        GLDS16(src + blk * 64 + lane, &As[blk * 64]);
    }
    __syncthreads();

    const int b128 = wave >> 1;                // 128-col B block
    const int nt0 = (wave & 1) * 4;            // first 16-col tile inside it
    const s16x8* wt = (const s16x8*)Wt;

    f32x4 acc[2][4];
#pragma unroll
    for (int i = 0; i < 2; ++i)
#pragma unroll
        for (int j = 0; j < 4; ++j)
            acc[i][j] = (f32x4){0.f, 0.f, 0.f, 0.f};

#pragma unroll 4
    for (int c = 0; c < 24; ++c) {
        b16x8 areg[2], breg[4];
        areg[0] = __builtin_bit_cast(b16x8, As[c * 64 + lane]);
        areg[1] = __builtin_bit_cast(b16x8, As[(24 + c) * 64 + lane]);
        size_t bb = (size_t)(c * 2 + b128) * 512 + nt0 * 64 + lane;
#pragma unroll
        for (int j = 0; j < 4; ++j)
            breg[j] = __builtin_bit_cast(b16x8, wt[bb + j * 64]);
#pragma unroll
        for (int i = 0; i < 2; ++i)
#pragma unroll
            for (int j = 0; j < 4; ++j)
                acc[i][j] = __builtin_amdgcn_mfma_f32_16x16x32_bf16(areg[i], breg[j], acc[i][j], 0, 0, 0);
    }

    const int quad = lane >> 4;
    const int nl = lane & 15;
#pragma unroll
    for (int i = 0; i < 2; ++i) {
        int rbase = m0 + i * 16 + quad * 4;
#pragma unroll
        for (int j = 0; j < 4; ++j) {
            int col = wave * 64 + j * 16 + nl;
#pragma unroll
            for (int rr = 0; rr < 4; ++rr) {
                int row = rbase + rr;
                if (row < M) Cb[(size_t)row * 256 + col] = (unsigned short)f2bf(acc[i][j][rr]);
            }
        }
    }
}

// ---------------- row-panel GEMM (bf16 A, used for layer 2) ----------------

template<typename AT, int KC, int RT, int CW, int MINW>
__global__ __launch_bounds__(256, MINW) void gemm_panel_kernel(
        const AT* __restrict__ A, const short* __restrict__ Wt,
        unsigned short* __restrict__ Cb, int M) {
    constexpr int K = KC * 32;
    constexpr int O = KC * 4;              // 8-elem octets per row
    constexpr int F = KC * RT / 4;         // frags staged per thread
    constexpr int NCOLS = CW * 64;
    constexpr int NB = NCOLS >> 7;         // 128-col B blocks
    constexpr int MT = RT * CW / 4;        // m-tiles per wave

    __shared__ s16x8 As[KC * RT * 64];

    const int tid = threadIdx.x;
    const int m0 = blockIdx.x * (RT * 16);

    s16x8 v[F];
#pragma unroll
    for (int i = 0; i < F; ++i) {
        int idx = i * 256 + tid;
        int r = idx / O;
        int o = idx - r * O;
        int row = m0 + r;
        if (row >= M) row = M - 1;
        v[i] = *(const s16x8*)((const unsigned short*)A + (size_t)row * K + o * 8);
    }
#pragma unroll
    for (int i = 0; i < F; ++i) {
        int idx = i * 256 + tid;
        int r = idx / O;
        int o = idx - r * O;
        int c = o >> 2, q = o & 3;
        int slot = q * 16 + (((r & 15) + q + ((c & 3) << 2)) & 15);
        As[(c * RT + (r >> 4)) * 64 + slot] = v[i];
    }
    __syncthreads();

    const int lane = tid & 63;
    const int wave = tid >> 6;
    const int cw_i = wave % CW;
    const int rg = wave / CW;
    const int mtb = rg * MT;
    const int b128 = (cw_i * 64) >> 7;
    const int nt0 = (cw_i * 4) & 7;
    const int q = lane >> 4;
    const int rl = lane & 15;
    const s16x8* wt = (const s16x8*)Wt;

    f32x4 acc[MT][4];
#pragma unroll
    for (int i = 0; i < MT; ++i)
#pragma unroll
        for (int j = 0; j < 4; ++j)
            acc[i][j] = (f32x4){0.f, 0.f, 0.f, 0.f};

#pragma unroll 4
    for (int c = 0; c < KC; ++c) {
        int slot = q * 16 + ((rl + q + ((c & 3) << 2)) & 15);
        b16x8 areg[MT], breg[4];
#pragma unroll
        for (int i = 0; i < MT; ++i)
            areg[i] = __builtin_bit_cast(b16x8, As[(c * RT + mtb + i) * 64 + slot]);
        size_t bb = (size_t)(c * NB + b128) * 512 + nt0 * 64 + lane;
#pragma unroll
        for (int j = 0; j < 4; ++j)
            breg[j] = __builtin_bit_cast(b16x8, wt[bb + j * 64]);
#pragma unroll
        for (int i = 0; i < MT; ++i)
#pragma unroll
            for (int j = 0; j < 4; ++j)
                acc[i][j] = __builtin_amdgcn_mfma_f32_16x16x32_bf16(areg[i], breg[j], acc[i][j], 0, 0, 0);
    }

    const int quad = lane >> 4;
    const int nl = lane & 15;
#pragma unroll
    for (int i = 0; i < MT; ++i) {
        int rbase = m0 + (mtb + i) * 16 + quad * 4;
#pragma unroll
        for (int j = 0; j < 4; ++j) {
            int col = cw_i * 64 + j * 16 + nl;
#pragma unroll
            for (int rr = 0; rr < 4; ++rr) {
                int row = rbase + rr;
                if (row < M) Cb[(size_t)row * NCOLS + col] = (unsigned short)f2bf(acc[i][j][rr]);
            }
        }
    }
}

// ---------------- aggregation, bf16 in ----------------

__global__ __launch_bounds__(256) void agg256_kernel(const unsigned short* __restrict__ h,
                                                     const int* __restrict__ rp,
                                                     const int* __restrict__ csrc,
                                                     const float* __restrict__ cw,
                                                     const float* __restrict__ dinv,
                                                     const float* __restrict__ bias,
                                                     unsigned short* __restrict__ out, int n) {
    int node = blockIdx.x * 4 + (threadIdx.x >> 6);
    int lane = threadIdx.x & 63;
    if (node >= n) return;
    const ushort4* hp = (const ushort4*)h;       // 64 per row
    float di = dinv[node];
    float ws = di * di;
    ushort4 sv = hp[(size_t)node * 64 + lane];
    float a0 = ws * bf2f(sv.x), a1 = ws * bf2f(sv.y), a2 = ws * bf2f(sv.z), a3 = ws * bf2f(sv.w);
    int e = rp[node], e1 = rp[node + 1];
    for (; e + 1 < e1; e += 2) {
        int s0 = csrc[e], s1 = csrc[e + 1];
        float w0 = cw[e], w1 = cw[e + 1];
        ushort4 v0 = hp[(size_t)s0 * 64 + lane];
        ushort4 v1 = hp[(size_t)s1 * 64 + lane];
        a0 += w0 * bf2f(v0.x) + w1 * bf2f(v1.x);
        a1 += w0 * bf2f(v0.y) + w1 * bf2f(v1.y);
        a2 += w0 * bf2f(v0.z) + w1 * bf2f(v1.z);
        a3 += w0 * bf2f(v0.w) + w1 * bf2f(v1.w);
    }
    if (e < e1) {
        int s0 = csrc[e];
        float w0 = cw[e];
        ushort4 v0 = hp[(size_t)s0 * 64 + lane];
        a0 += w0 * bf2f(v0.x); a1 += w0 * bf2f(v0.y);
        a2 += w0 * bf2f(v0.z); a3 += w0 * bf2f(v0.w);
    }
    float4 bv = *(const float4*)&bias[lane * 4];
    a0 = fmaxf(a0 + bv.x, 0.f); a1 = fmaxf(a1 + bv.y, 0.f);
    a2 = fmaxf(a2 + bv.z, 0.f); a3 = fmaxf(a3 + bv.w, 0.f);
    ushort4 ov;
    ov.x = (unsigned short)f2bf(a0); ov.y = (unsigned short)f2bf(a1);
    ov.z = (unsigned short)f2bf(a2); ov.w = (unsigned short)f2bf(a3);
    ((ushort4*)out)[(size_t)node * 64 + lane] = ov;
}

__global__ __launch_bounds__(256) void agg128_w3_kernel(const unsigned short* __restrict__ h,
                                                        const int* __restrict__ rp,
                                                        const int* __restrict__ csrc,
                                                        const float* __restrict__ cw,
                                                        const float* __restrict__ dinv,
                                                        const float* __restrict__ b2,
                                                        const float* __restrict__ W3,
                                                        float* __restrict__ z, int n) {
    int node = blockIdx.x * 4 + (threadIdx.x >> 6);
    int lane = threadIdx.x & 63;
    if (node >= n) return;
    const unsigned* hp = (const unsigned*)h;     // 64 uints per row (2 bf16 each)
    float di = dinv[node];
    float ws = di * di;
    unsigned sv = hp[(size_t)node * 64 + lane];
    float a0 = ws * __uint_as_float(sv << 16);
    float a1 = ws * __uint_as_float(sv & 0xFFFF0000u);
    int e = rp[node], e1 = rp[node + 1];
    for (; e + 1 < e1; e += 2) {
        int s0 = csrc[e], s1 = csrc[e + 1];
        float w0 = cw[e], w1 = cw[e + 1];
        unsigned v0 = hp[(size_t)s0 * 64 + lane];
        unsigned v1 = hp[(size_t)s1 * 64 + lane];
        a0 += w0 * __uint_as_float(v0 << 16) + w1 * __uint_as_float(v1 << 16);
        a1 += w0 * __uint_as_float(v0 & 0xFFFF0000u) + w1 * __uint_as_float(v1 & 0xFFFF0000u);
    }
    if (e < e1) {
        int s0 = csrc[e];
        float w0 = cw[e];
        unsigned v0 = hp[(size_t)s0 * 64 + lane];
        a0 += w0 * __uint_as_float(v0 << 16);
        a1 += w0 * __uint_as_float(v0 & 0xFFFF0000u);
    }
    float2 bv = *(const float2*)&b2[lane * 2];
    a0 = fmaxf(a0 + bv.x, 0.f);
    a1 = fmaxf(a1 + bv.y, 0.f);
    float4 wv = *(const float4*)&W3[lane * 4];
    float z0 = a0 * wv.x + a1 * wv.z;
    float z1 = a0 * wv.y + a1 * wv.w;
    for (int off = 32; off > 0; off >>= 1) {
        z0 += __shfl_down(z0, off, 64);
        z1 += __shfl_down(z1, off, 64);
    }
    if (lane == 0) {
        z[2 * (size_t)node] = z0;
        z[2 * (size_t)node + 1] = z1;
    }
}

__global__ void agg3_kernel(const float* __restrict__ z, const int* __restrict__ rp,
                            const int* __restrict__ csrc, const float* __restrict__ cw,
                            const float* __restrict__ dinv, const float* __restrict__ bias,
                            float* __restrict__ out, int n) {
    int node = blockIdx.x * blockDim.x + threadIdx.x;
    if (node >= n) return;
    float di = dinv[node];
    float a0 = di * di * z[2 * (size_t)node];
    float a1 = di * di * z[2 * (size_t)node + 1];
    int e1 = rp[node + 1];
    for (int e = rp[node]; e < e1; ++e) {
        int s = csrc[e];
        float w = cw[e];
        a0 += w * z[2 * (size_t)s];
        a1 += w * z[2 * (size_t)s + 1];
    }
    a0 += bias[0];
    a1 += bias[1];
    out[2 * (size_t)node]     = 1.f / (1.f + __expf(-a0));
    out[2 * (size_t)node + 1] = 1.f / (1.f + __expf(-a1));
}

// ---------------- launch ----------------

extern "C" void kernel_launch(void* const* d_in, const int* in_sizes, int n_in,
                              void* d_out, int out_size, void* d_ws, size_t ws_size,
                              hipStream_t stream) {
    const float* x  = (const float*)d_in[0];
    const int*   ei = (const int*)d_in[1];
    const float* W1 = (const float*)d_in[2];
    const float* b1 = (const float*)d_in[3];
    const float* W2 = (const float*)d_in[4];
    const float* b2 = (const float*)d_in[5];
    const float* W3 = (const float*)d_in[6];
    const float* b3 = (const float*)d_in[7];
    float* out = (float*)d_out;

    const int E  = in_sizes[1] / 2;
    const int C1 = in_sizes[3];              // 256
    const int C2 = in_sizes[5];              // 128
    const int K1 = in_sizes[2] / C1;         // 768
    const int N  = in_sizes[0] / K1;         // 50000

    const int* srcv = ei;
    const int* dstv = ei + E;

    const int gblk = (N + 31) / 32;          // gemm1 blocks (1563)
    const int units = gblk * 3072;           // xf 16B units (48 KB per block)

    char* p = (char*)d_ws;
    auto carve = [&](size_t bytes) {
        char* r = p;
        p += (bytes + 255) & ~(size_t)255;
        return r;
    };
    int*   cnt    = (int*)carve((size_t)N * 4);
    int*   rp     = (int*)carve((size_t)(N + 1) * 4);
    int*   cursor = (int*)carve((size_t)N * 4);
    float* dinv   = (float*)carve((size_t)N * 4);
    int*   bsum   = (int*)carve(1024 * 4);
    int*   csrc   = (int*)carve((size_t)E * 4);
    float* cw     = (float*)carve((size_t)E * 4);
    short* Wt1    = (short*)carve((size_t)K1 * C1 * 2);
    short* Wt2    = (short*)carve((size_t)C1 * C2 * 2);
    unsigned short* hA = (unsigned short*)carve((size_t)N * C1 * 2);
    // overlay region: xf (conv->gemm1) later reused for hB (agg256->gemm2) + zbuf
    char*  R      = carve((size_t)units * 16);
    s16x8* xf     = (s16x8*)R;
    unsigned short* hB = (unsigned short*)R;
    float* zbuf   = (float*)(R + (((size_t)N * C1 * 2 + 255) & ~(size_t)255));

    const int nb = (N + 1023) / 1024;

    // x -> frag-ready bf16 (first: large, BW-bound)
    convx_kernel<<<(units + 255) / 256, 256, 0, stream>>>(x, xf, N, units);

    // CSR build
    hipMemsetAsync(cnt, 0, (size_t)N * 4, stream);
    count_kernel<<<(E + 255) / 256, 256, 0, stream>>>(dstv, cnt, E);
    blockscan_kernel<<<nb, 1024, 0, stream>>>(cnt, rp, bsum, N);
    topscan_kernel<<<1, 64, 0, stream>>>(bsum, nb);
    fixup_kernel<<<nb, 1024, 0, stream>>>(rp, bsum, cnt, cursor, dinv, N, E);
    fill_kernel<<<(E + 255) / 256, 256, 0, stream>>>(srcv, dstv, cursor, dinv, csrc, cw, E);

    // Weight pre-transpose (fragment-ready bf16)
    make_wt_kernel<<<(K1 * C1 + 255) / 256, 256, 0, stream>>>(W1, Wt1, K1, C1);
    make_wt_kernel<<<(C1 * C2 + 255) / 256, 256, 0, stream>>>(W2, Wt2, C1, C2);

    // Layer 1: h1 = x @ W1 (GLDS frag-ready) ; a1 = relu(Ahat h1 + b1)
    gemm1_kernel<<<gblk, 256, 0, stream>>>(xf, Wt1, hA, N);
    agg256_kernel<<<(N + 3) / 4, 256, 0, stream>>>(hA, rp, csrc, cw, dinv, b1, hB, N);

    // Layer 2: h2 = a1 @ W2 (64-row panels) ; fused a2+W3
    gemm_panel_kernel<unsigned short, 8, 4, 2, 4><<<(N + 63) / 64, 256, 0, stream>>>(hB, Wt2, hA, N);
    agg128_w3_kernel<<<(N + 3) / 4, 256, 0, stream>>>(hA, rp, csrc, cw, dinv, b2, W3, zbuf, N);

    // Layer 3 aggregation + sigmoid
    agg3_kernel<<<(N + 255) / 256, 256, 0, stream>>>(zbuf, rp, csrc, cw, dinv, b3, out, N);
}

// Round 9
// 489.464 us; speedup vs baseline: 1.0597x; 1.0597x over previous
//
#include <hip/hip_runtime.h>
#include <math.h>

typedef short s16x8 __attribute__((ext_vector_type(8)));
typedef __bf16 b16x8 __attribute__((ext_vector_type(8)));
typedef float f32x4 __attribute__((ext_vector_type(4)));
typedef float f32x2 __attribute__((ext_vector_type(2)));
typedef unsigned int u32x4 __attribute__((ext_vector_type(4)));

__device__ inline short f2bf(float f) {
    unsigned u = __float_as_uint(f);
    unsigned r = u + 0x7FFFu + ((u >> 16) & 1u);   // RNE
    return (short)(r >> 16);
}
__device__ inline float bf2f(unsigned short u) {
    return __uint_as_float(((unsigned)u) << 16);
}

// async global->LDS, 16B per lane; lds dest = wave-uniform base + lane*16
#define GLDS16(g, l)                                                            \
    __builtin_amdgcn_global_load_lds(                                           \
        (const __attribute__((address_space(1))) void*)(g),                     \
        (__attribute__((address_space(3))) void*)(l), 16, 0, 0)

// ---------------- fused prep: count + make_wt1 + make_wt2 ----------------
// Wt chunk layout: [c = k0/32][b = n0/128][nt 0..7][lane 0..63][j 0..7]
//   value = W[c*32 + (lane>>4)*8 + j][b*128 + nt*16 + (lane&15)]

__device__ inline void make_wt_elem(const float* __restrict__ W, short* __restrict__ Wt,
                                    int K, int N, int idx) {
    int NB = N >> 7;
    int j = idx & 7;
    int l = (idx >> 3) & 63;
    int nt = (idx >> 9) & 7;
    int rest = idx >> 12;
    int b = rest % NB;
    int c = rest / NB;
    int k = c * 32 + (l >> 4) * 8 + j;
    int n = b * 128 + nt * 16 + (l & 15);
    Wt[idx] = f2bf(W[(size_t)k * N + n]);
}

__global__ void prep_kernel(const int* __restrict__ dst, int* __restrict__ cnt, int E,
                            const float* __restrict__ W1, short* __restrict__ Wt1,
                            const float* __restrict__ W2, short* __restrict__ Wt2,
                            int cb, int w1b) {
    int b = blockIdx.x;
    int tid = threadIdx.x;
    if (b < cb) {
        int e = b * 256 + tid;
        if (e < E) atomicAdd(&cnt[dst[e]], 1);
    } else if (b < cb + w1b) {
        int idx = (b - cb) * 256 + tid;
        make_wt_elem(W1, Wt1, 768, 256, idx);
    } else {
        int idx = (b - cb - w1b) * 256 + tid;
        make_wt_elem(W2, Wt2, 256, 128, idx);
    }
}

// ---------------- CSR scan chain ----------------

__global__ __launch_bounds__(1024) void blockscan_kernel(const int* __restrict__ cnt,
                                                         int* __restrict__ rp,
                                                         int* __restrict__ bsum, int n) {
    __shared__ int sdata[1024];
    int tid = threadIdx.x;
    int i = blockIdx.x * 1024 + tid;
    int v = (i < n) ? cnt[i] : 0;
    sdata[tid] = v;
    __syncthreads();
    for (int off = 1; off < 1024; off <<= 1) {
        int t = 0;
        if (tid >= off) t = sdata[tid - off];
        __syncthreads();
        sdata[tid] += t;
        __syncthreads();
    }
    if (i < n) rp[i] = sdata[tid] - v;       // local exclusive
    if (tid == 1023) bsum[blockIdx.x] = sdata[1023];
}

__global__ void topscan_kernel(int* bsum, int nb) {
    int lane = threadIdx.x;                   // 64 threads
    int carry = 0;
    for (int base = 0; base < nb; base += 64) {
        int idx = base + lane;
        int orig = (idx < nb) ? bsum[idx] : 0;
        int v = orig;
        for (int off = 1; off < 64; off <<= 1) {
            int t = __shfl_up(v, off, 64);
            if (lane >= off) v += t;
        }
        if (idx < nb) bsum[idx] = carry + v - orig;   // exclusive
        carry += __shfl(v, 63, 64);
    }
}

__global__ __launch_bounds__(1024) void fixup_kernel(int* __restrict__ rp,
                                                     const int* __restrict__ bsum,
                                                     const int* __restrict__ cnt,
                                                     int* __restrict__ cursor,
                                                     float* __restrict__ dinv,
                                                     int n, int E) {
    int i = blockIdx.x * 1024 + threadIdx.x;
    if (i < n) {
        int r = rp[i] + bsum[blockIdx.x];
        rp[i] = r;
        cursor[i] = r;
        dinv[i] = rsqrtf((float)cnt[i] + 1.0f);
    }
    if (i == 0) rp[n] = E;
}

__global__ void fill_kernel(const int* __restrict__ src, const int* __restrict__ dst,
                            int* __restrict__ cursor, const float* __restrict__ dinv,
                            int* __restrict__ csrc, float* __restrict__ cw, int E) {
    int e = blockIdx.x * blockDim.x + threadIdx.x;
    if (e >= E) return;
    int d = dst[e];
    int s = src[e];
    int p = atomicAdd(&cursor[d], 1);
    csrc[p] = s;
    cw[p] = dinv[s] * dinv[d];
}

// ---------------- GEMM1: h1(fp8)[M x 256] = x(fp32) @ Wt1(frag-ready bf16) ----------------
// Block = 16 rows x 256 cols, 256 threads = 4 waves (wave w -> cols w*64..).
// Stage 16 FULL fp32 rows (48 KB) via 48 coalesced 1KB global_load_lds, ONE barrier.
// Barrier-free K-loop: ds_read fp32 pairs -> bf16 truncation pack -> MFMA;
// B frags streamed from L2-resident Wt1. Epilogue stores fp8 e4m3 bytes.
// Requires M % 16 == 0 (50000 = 3125*16).

__global__ __launch_bounds__(256, 3) void gemm1_kernel(const float* __restrict__ x,
                                                       const short* __restrict__ Wt,
                                                       unsigned char* __restrict__ h8,
                                                       int M) {
    __shared__ float As[16 * 768];             // 48 KB, row-major, stride 768 floats

    const int tid = threadIdx.x;
    const int lane = tid & 63;
    const int wave = tid >> 6;
    const int m0 = blockIdx.x * 16;

#pragma unroll
    for (int i = 0; i < 12; ++i) {
        int unit = wave * 12 + i;              // 0..47
        int row = unit / 3;                    // 0..15
        int ch = unit - row * 3;               // 0..2 (1 KB chunks of the 3 KB row)
        GLDS16(x + (size_t)(m0 + row) * 768 + ch * 256 + lane * 4,
               &As[row * 768 + ch * 256]);
    }
    __syncthreads();

    const int q = lane >> 4;                   // k-octet 0..3
    const int ml = lane & 15;                  // row within tile
    const int b128 = wave >> 1;                // 128-col B block
    const int nt0 = (wave & 1) * 4;            // first 16-col tile inside it
    const s16x8* wt = (const s16x8*)Wt;
    const float4* af = (const float4*)As;

    f32x4 acc[4];
#pragma unroll
    for (int j = 0; j < 4; ++j) acc[j] = (f32x4){0.f, 0.f, 0.f, 0.f};

#pragma unroll 4
    for (int c = 0; c < 24; ++c) {
        int fi = ml * 192 + c * 8 + q * 2;     // float4 index
        float4 f0 = af[fi];
        float4 f1 = af[fi + 1];
        u32x4 pk;
        pk.x = (__float_as_uint(f0.x) >> 16) | (__float_as_uint(f0.y) & 0xFFFF0000u);
        pk.y = (__float_as_uint(f0.z) >> 16) | (__float_as_uint(f0.w) & 0xFFFF0000u);
        pk.z = (__float_as_uint(f1.x) >> 16) | (__float_as_uint(f1.y) & 0xFFFF0000u);
        pk.w = (__float_as_uint(f1.z) >> 16) | (__float_as_uint(f1.w) & 0xFFFF0000u);
        b16x8 areg = __builtin_bit_cast(b16x8, pk);

        b16x8 breg[4];
        size_t bb = (size_t)(c * 2 + b128) * 512 + nt0 * 64 + lane;
#pragma unroll
        for (int j = 0; j < 4; ++j)
            breg[j] = __builtin_bit_cast(b16x8, wt[bb + j * 64]);
#pragma unroll
        for (int j = 0; j < 4; ++j)
            acc[j] = __builtin_amdgcn_mfma_f32_16x16x32_bf16(areg, breg[j], acc[j], 0, 0, 0);
    }

    const int quad = lane >> 4;
    const int nl = lane & 15;
#pragma unroll
    for (int j = 0; j < 4; ++j) {
        int col = wave * 64 + j * 16 + nl;
#pragma unroll
        for (int r = 0; r < 4; ++r) {
            int row = m0 + quad * 4 + r;
            unsigned u = __builtin_amdgcn_cvt_pk_fp8_f32(acc[j][r], acc[j][r], 0, false);
            h8[(size_t)row * 256 + col] = (unsigned char)(u & 0xFF);
        }
    }
}

// ---------------- row-panel GEMM (bf16 A, layer 2) ----------------

template<typename AT, int KC, int RT, int CW, int MINW>
__global__ __launch_bounds__(256, MINW) void gemm_panel_kernel(
        const AT* __restrict__ A, const short* __restrict__ Wt,
        unsigned short* __restrict__ Cb, int M) {
    constexpr int K = KC * 32;
    constexpr int O = KC * 4;              // 8-elem octets per row
    constexpr int F = KC * RT / 4;         // frags staged per thread
    constexpr int NCOLS = CW * 64;
    constexpr int NB = NCOLS >> 7;         // 128-col B blocks
    constexpr int MT = RT * CW / 4;        // m-tiles per wave

    __shared__ s16x8 As[KC * RT * 64];

    const int tid = threadIdx.x;
    const int m0 = blockIdx.x * (RT * 16);

    s16x8 v[F];
#pragma unroll
    for (int i = 0; i < F; ++i) {
        int idx = i * 256 + tid;
        int r = idx / O;
        int o = idx - r * O;
        int row = m0 + r;
        if (row >= M) row = M - 1;
        v[i] = *(const s16x8*)((const unsigned short*)A + (size_t)row * K + o * 8);
    }
#pragma unroll
    for (int i = 0; i < F; ++i) {
        int idx = i * 256 + tid;
        int r = idx / O;
        int o = idx - r * O;
        int c = o >> 2, q = o & 3;
        int slot = q * 16 + (((r & 15) + q + ((c & 3) << 2)) & 15);
        As[(c * RT + (r >> 4)) * 64 + slot] = v[i];
    }
    __syncthreads();

    const int lane = tid & 63;
    const int wave = tid >> 6;
    const int cw_i = wave % CW;
    const int rg = wave / CW;
    const int mtb = rg * MT;
    const int b128 = (cw_i * 64) >> 7;
    const int nt0 = (cw_i * 4) & 7;
    const int q = lane >> 4;
    const int rl = lane & 15;
    const s16x8* wt = (const s16x8*)Wt;

    f32x4 acc[MT][4];
#pragma unroll
    for (int i = 0; i < MT; ++i)
#pragma unroll
        for (int j = 0; j < 4; ++j)
            acc[i][j] = (f32x4){0.f, 0.f, 0.f, 0.f};

#pragma unroll 4
    for (int c = 0; c < KC; ++c) {
        int slot = q * 16 + ((rl + q + ((c & 3) << 2)) & 15);
        b16x8 areg[MT], breg[4];
#pragma unroll
        for (int i = 0; i < MT; ++i)
            areg[i] = __builtin_bit_cast(b16x8, As[(c * RT + mtb + i) * 64 + slot]);
        size_t bb = (size_t)(c * NB + b128) * 512 + nt0 * 64 + lane;
#pragma unroll
        for (int j = 0; j < 4; ++j)
            breg[j] = __builtin_bit_cast(b16x8, wt[bb + j * 64]);
#pragma unroll
        for (int i = 0; i < MT; ++i)
#pragma unroll
            for (int j = 0; j < 4; ++j)
                acc[i][j] = __builtin_amdgcn_mfma_f32_16x16x32_bf16(areg[i], breg[j], acc[i][j], 0, 0, 0);
    }

    const int quad = lane >> 4;
    const int nl = lane & 15;
#pragma unroll
    for (int i = 0; i < MT; ++i) {
        int rbase = m0 + (mtb + i) * 16 + quad * 4;
#pragma unroll
        for (int j = 0; j < 4; ++j) {
            int col = cw_i * 64 + j * 16 + nl;
#pragma unroll
            for (int rr = 0; rr < 4; ++rr) {
                int row = rbase + rr;
                if (row < M) Cb[(size_t)row * NCOLS + col] = (unsigned short)f2bf(acc[i][j][rr]);
            }
        }
    }
}

// ---------------- aggregation ----------------
// Layer 1: gather fp8 e4m3 h1, relu(agg + b1) -> bf16 a1. Wave per node, lane = 4 ch.

__global__ __launch_bounds__(256) void agg256_f8_kernel(const unsigned char* __restrict__ h8,
                                                        const int* __restrict__ rp,
                                                        const int* __restrict__ csrc,
                                                        const float* __restrict__ cw,
                                                        const float* __restrict__ dinv,
                                                        const float* __restrict__ bias,
                                                        unsigned short* __restrict__ out, int n) {
    int node = blockIdx.x * 4 + (threadIdx.x >> 6);
    int lane = threadIdx.x & 63;
    if (node >= n) return;
    const unsigned* hp = (const unsigned*)h8;    // 64 uints per row (4 fp8 each)
    float di = dinv[node];
    float ws = di * di;
    unsigned sv = hp[(size_t)node * 64 + lane];
    f32x2 slo = __builtin_amdgcn_cvt_pk_f32_fp8(sv, false);
    f32x2 shi = __builtin_amdgcn_cvt_pk_f32_fp8(sv, true);
    float a0 = ws * slo.x, a1 = ws * slo.y, a2 = ws * shi.x, a3 = ws * shi.y;
    int e = rp[node], e1 = rp[node + 1];
    for (; e + 1 < e1; e += 2) {
        int s0 = csrc[e], s1 = csrc[e + 1];
        float w0 = cw[e], w1 = cw[e + 1];
        unsigned v0 = hp[(size_t)s0 * 64 + lane];
        unsigned v1 = hp[(size_t)s1 * 64 + lane];
        f32x2 l0 = __builtin_amdgcn_cvt_pk_f32_fp8(v0, false);
        f32x2 h0 = __builtin_amdgcn_cvt_pk_f32_fp8(v0, true);
        f32x2 l1 = __builtin_amdgcn_cvt_pk_f32_fp8(v1, false);
        f32x2 h1 = __builtin_amdgcn_cvt_pk_f32_fp8(v1, true);
        a0 += w0 * l0.x + w1 * l1.x;
        a1 += w0 * l0.y + w1 * l1.y;
        a2 += w0 * h0.x + w1 * h1.x;
        a3 += w0 * h0.y + w1 * h1.y;
    }
    if (e < e1) {
        int s0 = csrc[e];
        float w0 = cw[e];
        unsigned v0 = hp[(size_t)s0 * 64 + lane];
        f32x2 l0 = __builtin_amdgcn_cvt_pk_f32_fp8(v0, false);
        f32x2 h0 = __builtin_amdgcn_cvt_pk_f32_fp8(v0, true);
        a0 += w0 * l0.x; a1 += w0 * l0.y; a2 += w0 * h0.x; a3 += w0 * h0.y;
    }
    float4 bv = *(const float4*)&bias[lane * 4];
    a0 = fmaxf(a0 + bv.x, 0.f); a1 = fmaxf(a1 + bv.y, 0.f);
    a2 = fmaxf(a2 + bv.z, 0.f); a3 = fmaxf(a3 + bv.w, 0.f);
    ushort4 ov;
    ov.x = (unsigned short)f2bf(a0); ov.y = (unsigned short)f2bf(a1);
    ov.z = (unsigned short)f2bf(a2); ov.w = (unsigned short)f2bf(a3);
    ((ushort4*)out)[(size_t)node * 64 + lane] = ov;
}

// Layer 2 fused with W3: gather bf16 h2, a2 = relu(agg+b2); z = a2 @ W3 (128x2).
__global__ __launch_bounds__(256) void agg128_w3_kernel(const unsigned short* __restrict__ h,
                                                        const int* __restrict__ rp,
                                                        const int* __restrict__ csrc,
                                                        const float* __restrict__ cw,
                                                        const float* __restrict__ dinv,
                                                        const float* __restrict__ b2,
                                                        const float* __restrict__ W3,
                                                        float* __restrict__ z, int n) {
    int node = blockIdx.x * 4 + (threadIdx.x >> 6);
    int lane = threadIdx.x & 63;
    if (node >= n) return;
    const unsigned* hp = (const unsigned*)h;     // 64 uints per row (2 bf16 each)
    float di = dinv[node];
    float ws = di * di;
    unsigned sv = hp[(size_t)node * 64 + lane];
    float a0 = ws * __uint_as_float(sv << 16);
    float a1 = ws * __uint_as_float(sv & 0xFFFF0000u);
    int e = rp[node], e1 = rp[node + 1];
    for (; e + 1 < e1; e += 2) {
        int s0 = csrc[e], s1 = csrc[e + 1];
        float w0 = cw[e], w1 = cw[e + 1];
        unsigned v0 = hp[(size_t)s0 * 64 + lane];
        unsigned v1 = hp[(size_t)s1 * 64 + lane];
        a0 += w0 * __uint_as_float(v0 << 16) + w1 * __uint_as_float(v1 << 16);
        a1 += w0 * __uint_as_float(v0 & 0xFFFF0000u) + w1 * __uint_as_float(v1 & 0xFFFF0000u);
    }
    if (e < e1) {
        int s0 = csrc[e];
        float w0 = cw[e];
        unsigned v0 = hp[(size_t)s0 * 64 + lane];
        a0 += w0 * __uint_as_float(v0 << 16);
        a1 += w0 * __uint_as_float(v0 & 0xFFFF0000u);
    }
    float2 bv = *(const float2*)&b2[lane * 2];
    a0 = fmaxf(a0 + bv.x, 0.f);
    a1 = fmaxf(a1 + bv.y, 0.f);
    float4 wv = *(const float4*)&W3[lane * 4];
    float z0 = a0 * wv.x + a1 * wv.z;
    float z1 = a0 * wv.y + a1 * wv.w;
    for (int off = 32; off > 0; off >>= 1) {
        z0 += __shfl_down(z0, off, 64);
        z1 += __shfl_down(z1, off, 64);
    }
    if (lane == 0) {
        z[2 * (size_t)node] = z0;
        z[2 * (size_t)node + 1] = z1;
    }
}

__global__ void agg3_kernel(const float* __restrict__ z, const int* __restrict__ rp,
                            const int* __restrict__ csrc, const float* __restrict__ cw,
                            const float* __restrict__ dinv, const float* __restrict__ bias,
                            float* __restrict__ out, int n) {
    int node = blockIdx.x * blockDim.x + threadIdx.x;
    if (node >= n) return;
    float di = dinv[node];
    float a0 = di * di * z[2 * (size_t)node];
    float a1 = di * di * z[2 * (size_t)node + 1];
    int e1 = rp[node + 1];
    for (int e = rp[node]; e < e1; ++e) {
        int s = csrc[e];
        float w = cw[e];
        a0 += w * z[2 * (size_t)s];
        a1 += w * z[2 * (size_t)s + 1];
    }
    a0 += bias[0];
    a1 += bias[1];
    out[2 * (size_t)node]     = 1.f / (1.f + __expf(-a0));
    out[2 * (size_t)node + 1] = 1.f / (1.f + __expf(-a1));
}

// ---------------- launch ----------------

extern "C" void kernel_launch(void* const* d_in, const int* in_sizes, int n_in,
                              void* d_out, int out_size, void* d_ws, size_t ws_size,
                              hipStream_t stream) {
    const float* x  = (const float*)d_in[0];
    const int*   ei = (const int*)d_in[1];
    const float* W1 = (const float*)d_in[2];
    const float* b1 = (const float*)d_in[3];
    const float* W2 = (const float*)d_in[4];
    const float* b2 = (const float*)d_in[5];
    const float* W3 = (const float*)d_in[6];
    const float* b3 = (const float*)d_in[7];
    float* out = (float*)d_out;

    const int E  = in_sizes[1] / 2;
    const int C1 = in_sizes[3];              // 256
    const int C2 = in_sizes[5];              // 128
    const int K1 = in_sizes[2] / C1;         // 768
    const int N  = in_sizes[0] / K1;         // 50000

    const int* srcv = ei;
    const int* dstv = ei + E;

    char* p = (char*)d_ws;
    auto carve = [&](size_t bytes) {
        char* r = p;
        p += (bytes + 255) & ~(size_t)255;
        return r;
    };
    int*   cnt    = (int*)carve((size_t)N * 4);
    int*   rp     = (int*)carve((size_t)(N + 1) * 4);
    int*   cursor = (int*)carve((size_t)N * 4);
    float* dinv   = (float*)carve((size_t)N * 4);
    int*   bsum   = (int*)carve(1024 * 4);
    int*   csrc   = (int*)carve((size_t)E * 4);
    float* cw     = (float*)carve((size_t)E * 4);
    short* Wt1    = (short*)carve((size_t)K1 * C1 * 2);
    short* Wt2    = (short*)carve((size_t)C1 * C2 * 2);
    unsigned char* h8 = (unsigned char*)carve((size_t)N * C1);       // fp8 h1
    unsigned short* hB = (unsigned short*)carve((size_t)N * C1 * 2); // bf16 a1
    unsigned short* h2 = (unsigned short*)carve((size_t)N * C2 * 2); // bf16 h2
    float* zbuf   = (float*)carve((size_t)N * 2 * 4);

    const int nb = (N + 1023) / 1024;
    const int cb = (E + 255) / 256;
    const int w1b = (K1 * C1) / 256;         // 768
    const int w2b = (C1 * C2) / 256;         // 128

    // CSR + weight prep (fused)
    hipMemsetAsync(cnt, 0, (size_t)N * 4, stream);
    prep_kernel<<<cb + w1b + w2b, 256, 0, stream>>>(dstv, cnt, E, W1, Wt1, W2, Wt2, cb, w1b);
    blockscan_kernel<<<nb, 1024, 0, stream>>>(cnt, rp, bsum, N);
    topscan_kernel<<<1, 64, 0, stream>>>(bsum, nb);
    fixup_kernel<<<nb, 1024, 0, stream>>>(rp, bsum, cnt, cursor, dinv, N, E);
    fill_kernel<<<(E + 255) / 256, 256, 0, stream>>>(srcv, dstv, cursor, dinv, csrc, cw, E);

    // Layer 1: h1 = x @ W1 (direct fp32 GLDS, fp8 out) ; a1 = relu(Ahat h1 + b1)
    gemm1_kernel<<<N / 16, 256, 0, stream>>>(x, Wt1, h8, N);
    agg256_f8_kernel<<<(N + 3) / 4, 256, 0, stream>>>(h8, rp, csrc, cw, dinv, b1, hB, N);

    // Layer 2: h2 = a1 @ W2 (64-row panels) ; fused a2 = relu(agg+b2), z = a2 @ W3
    gemm_panel_kernel<unsigned short, 8, 4, 2, 4><<<(N + 63) / 64, 256, 0, stream>>>(hB, Wt2, h2, N);
    agg128_w3_kernel<<<(N + 3) / 4, 256, 0, stream>>>(h2, rp, csrc, cw, dinv, b2, W3, zbuf, N);

    // Layer 3 aggregation + sigmoid
    agg3_kernel<<<(N + 255) / 256, 256, 0, stream>>>(zbuf, rp, csrc, cw, dinv, b3, out, N);
}